// Round 1
// 590.043 us; speedup vs baseline: 1.0490x; 1.0490x over previous
//
#include <hip/hip_runtime.h>

#define BTOT   131072
#define INDIM  128
#define OUTDIM 512
#define VBS    128
#define NCHUNK (BTOT / VBS)   // 1024
#define MAXIT  16
#define TTOL   1e-4f
#define EPS    1e-5f
#define TSTR   520            // tile row stride in halves (8 halves pad)

typedef _Float16 half8  __attribute__((ext_vector_type(8)));
typedef float    floatx4 __attribute__((ext_vector_type(4)));

// ---------------------------------------------------------------------------
// Kernel 0: convert W [512x128] fp32 -> fp16 into workspace (row-major [o][k])
// ---------------------------------------------------------------------------
__global__ void w_to_half_kernel(const float* __restrict__ W,
                                 _Float16* __restrict__ Wh) {
    int i = blockIdx.x * blockDim.x + threadIdx.x;   // float4 index, 0..16383
    const float4 v = ((const float4*)W)[i];
    union { _Float16 h[4]; uint2 u; } p;
    p.h[0] = (_Float16)v.x; p.h[1] = (_Float16)v.y;
    p.h[2] = (_Float16)v.z; p.h[3] = (_Float16)v.w;
    ((uint2*)Wh)[i] = p.u;
}

// ---------------------------------------------------------------------------
// Sparsemax over one row held by a 16-lane group, 32 values per lane.
// s,k reductions via 4-step shfl_xor (stays within the 16-lane group);
// tau via Michelot fixed point with group-uniform early exit.
// ---------------------------------------------------------------------------
__device__ __forceinline__ void sparsemax_row32(float (&x)[32], float* outp)
{
    // row max: in-lane tree (fmax is associative-safe) + 4 shfl steps
    float m[16];
    #pragma unroll
    for (int j = 0; j < 16; ++j) m[j] = fmaxf(x[2*j], x[2*j+1]);
    #pragma unroll
    for (int j = 0; j < 8; ++j)  m[j] = fmaxf(m[j], m[j+8]);
    #pragma unroll
    for (int j = 0; j < 4; ++j)  m[j] = fmaxf(m[j], m[j+4]);
    float mx = fmaxf(fmaxf(m[0], m[1]), fmaxf(m[2], m[3]));
    mx = fmaxf(mx, __shfl_xor(mx, 1));
    mx = fmaxf(mx, __shfl_xor(mx, 2));
    mx = fmaxf(mx, __shfl_xor(mx, 4));
    mx = fmaxf(mx, __shfl_xor(mx, 8));

    // Michelot: tau' = tau + (sum relu(x-tau) - 1)/count(x>tau); tau0 = max-1.
    // s,k uniform across the 16-lane group after reduction -> uniform break.
    float tau = mx - 1.0f;
    #pragma unroll 1
    for (int it = 0; it < MAXIT; ++it) {
        float s0=0.f, s1=0.f, s2=0.f, s3=0.f;
        float k0=0.f, k1=0.f, k2=0.f, k3=0.f;
        #pragma unroll
        for (int j = 0; j < 32; j += 4) {
            float d0 = x[j+0] - tau, d1 = x[j+1] - tau;
            float d2 = x[j+2] - tau, d3 = x[j+3] - tau;
            s0 += fmaxf(d0, 0.f); k0 += (d0 > 0.f) ? 1.f : 0.f;
            s1 += fmaxf(d1, 0.f); k1 += (d1 > 0.f) ? 1.f : 0.f;
            s2 += fmaxf(d2, 0.f); k2 += (d2 > 0.f) ? 1.f : 0.f;
            s3 += fmaxf(d3, 0.f); k3 += (d3 > 0.f) ? 1.f : 0.f;
        }
        float s = (s0 + s1) + (s2 + s3);
        float k = (k0 + k1) + (k2 + k3);
        s += __shfl_xor(s, 1); k += __shfl_xor(k, 1);
        s += __shfl_xor(s, 2); k += __shfl_xor(k, 2);
        s += __shfl_xor(s, 4); k += __shfl_xor(k, 4);
        s += __shfl_xor(s, 8); k += __shfl_xor(k, 8);
        float ntau = tau + (s - 1.0f) / k;
        float delta = fabsf(ntau - tau);
        tau = ntau;
        if (delta <= TTOL) break;
    }

    #pragma unroll
    for (int j = 0; j < 4; ++j) {
        float4 o0, o1;
        o0.x = fmaxf(x[j*8+0] - tau, 0.f);
        o0.y = fmaxf(x[j*8+1] - tau, 0.f);
        o0.z = fmaxf(x[j*8+2] - tau, 0.f);
        o0.w = fmaxf(x[j*8+3] - tau, 0.f);
        o1.x = fmaxf(x[j*8+4] - tau, 0.f);
        o1.y = fmaxf(x[j*8+5] - tau, 0.f);
        o1.z = fmaxf(x[j*8+6] - tau, 0.f);
        o1.w = fmaxf(x[j*8+7] - tau, 0.f);
        *(float4*)(outp + j*128)     = o0;
        *(float4*)(outp + j*128 + 4) = o1;
    }
}

// ---------------------------------------------------------------------------
// Fully fused: GEMM(fp16 MFMA) + GhostBN + priors + sparsemax, one block per
// virtual batch of 128 rows. 1024 threads = 16 waves.
//   GEMM: wave (w8 = w&7, ch = w>>3) owns rows w8*16..+15, cols ch*256..+255
//         as 16 MFMA 16x16x32 col-tiles -> 64 fp32 acc regs.
//   Tile: normalized values staged fp16 in LDS [128][520] (130 KB). BN stat
//         scratch overlays the tile region (dead before tile is written).
//   Sparsemax (NEW): row-parallel. Wave w owns rows w*8..+7 in TWO passes of
//         4 rows; 16 lanes per row, 32 values per lane in registers.
//         Priors for pass A are batch-issued BEFORE the phase-3 barrier
//         (acc regs dead by then) so the barrier's vmcnt drain doubles as
//         a 128-loads-in-flight BW-efficient fill. Reductions are 4-step
//         shfl_xor within the 16-lane group (vs 6-step across 64 lanes,
//         8 rows serial, in the old version).
// LDS total: 130 KB tile + 4 KB a/b = 134 KB -> 1 block/CU, 16 waves.
// ---------------------------------------------------------------------------
__global__ void __launch_bounds__(1024)
fused_all(const float* __restrict__ priors,
          const float* __restrict__ feat,
          const _Float16* __restrict__ Wh,
          const float* __restrict__ gamma,
          const float* __restrict__ beta,
          float* __restrict__ out)
{
    __shared__ __align__(16) _Float16 tile[VBS][TSTR];   // 133120 B
    __shared__ float lds_ab[2][OUTDIM];                  // 4096 B
    // stats overlay the tile region: consumed (phase 2) before tile writes
    float* lds_sum = (float*)&tile[0][0];                // [8][512]
    float* lds_sq  = lds_sum + 8 * OUTDIM;               // [8][512]

    const int tid   = threadIdx.x;
    const int w     = tid >> 6;      // wave 0..15
    const int lane  = tid & 63;
    const int i16   = lane & 15;
    const int quad  = lane >> 4;     // 0..3
    const int w8    = w & 7;         // row group 0..7
    const int ch    = w >> 3;        // col half 0..1
    const int chunk = blockIdx.x;
    const int row0  = chunk * VBS + w8 * 16;
    const int cb0   = ch * 256;

    // ---- A fragments: A[m=lane&15][k=quad*8+j] per 32-wide k-tile ----
    half8 afrag[4];
    {
        const float* ap = feat + (size_t)(row0 + i16) * INDIM + quad * 8;
        #pragma unroll
        for (int kt = 0; kt < 4; ++kt) {
            float4 v0 = *(const float4*)(ap + kt * 32);
            float4 v1 = *(const float4*)(ap + kt * 32 + 4);
            half8 h;
            h[0]=(_Float16)v0.x; h[1]=(_Float16)v0.y; h[2]=(_Float16)v0.z; h[3]=(_Float16)v0.w;
            h[4]=(_Float16)v1.x; h[5]=(_Float16)v1.y; h[6]=(_Float16)v1.z; h[7]=(_Float16)v1.w;
            afrag[kt] = h;
        }
    }

    // ---- Phase 1: GEMM (16 col-tiles) + per-column partial stats (fp32) ----
    // B[k=quad*8+j][n=lane&15] = W[cb0 + t*16 + n][k], streamed from L2.
    floatx4 acc[16];
    {
        const half8* wp0 = (const half8*)(Wh + (size_t)(cb0 + i16) * INDIM + quad * 8);
        #pragma unroll
        for (int t = 0; t < 16; ++t) {
            floatx4 c = {0.f, 0.f, 0.f, 0.f};
            #pragma unroll
            for (int kt = 0; kt < 4; ++kt) {
                half8 b = wp0[t * 256 + kt * 4];   // t*16 rows * 128 halves /8; kt*32 halves /8
                c = __builtin_amdgcn_mfma_f32_16x16x32_f16(afrag[kt], b, c, 0, 0, 0);
            }
            acc[t] = c;
            // sum over the wave's 16 rows for column cb0+t*16+i16
            float s = c.x + c.y + c.z + c.w;
            float q = c.x*c.x + c.y*c.y + c.z*c.z + c.w*c.w;
            s += __shfl_xor(s, 16); q += __shfl_xor(q, 16);
            s += __shfl_xor(s, 32); q += __shfl_xor(q, 32);
            if (quad == 0) {
                lds_sum[w8 * OUTDIM + cb0 + t * 16 + i16] = s;
                lds_sq [w8 * OUTDIM + cb0 + t * 16 + i16] = q;
            }
        }
    }
    __syncthreads();

    // ---- Phase 2: reduce stats across the 8 row-groups -> BN affine a,b ----
    if (tid < OUTDIM) {
        float s = 0.f, q = 0.f;
        #pragma unroll
        for (int j = 0; j < 8; ++j) {
            s += lds_sum[j * OUTDIM + tid];
            q += lds_sq [j * OUTDIM + tid];
        }
        float mean = s * (1.0f / VBS);
        float var  = q * (1.0f / VBS) - mean * mean;
        float rstd = 1.0f / sqrtf(var + EPS);
        float a = gamma[tid] * rstd;
        float b = beta[tid] - mean * a;
        lds_ab[0][tid] = a;
        lds_ab[1][tid] = b;
    }
    __syncthreads();

    // ---- Phase 3: normalize acc, pack fp16 into LDS tile (clobbers stats) ----
    {
        const int r0 = w8 * 16 + quad * 4;
        #pragma unroll
        for (int t = 0; t < 16; ++t) {
            const int c = cb0 + t * 16 + i16;
            const float a = lds_ab[0][c];
            const float b = lds_ab[1][c];
            floatx4 v = acc[t];
            tile[r0 + 0][c] = (_Float16)fmaf(v.x, a, b);
            tile[r0 + 1][c] = (_Float16)fmaf(v.y, a, b);
            tile[r0 + 2][c] = (_Float16)fmaf(v.z, a, b);
            tile[r0 + 3][c] = (_Float16)fmaf(v.w, a, b);
        }
    }

    // ---- Prefetch pass-A priors BEFORE the barrier: acc is dead here, so
    // register peak is low, and the barrier's vmcnt(0) drain runs with
    // 16 waves x 8 float4 loads in flight per CU (BW-paced, not latency). ----
    // Pass A rows: w*8 + quad; lane covers cols i16*8 + j*128 + {0..7}.
    const size_t gbaseA = (size_t)(chunk * VBS + w * 8 + quad) * OUTDIM + i16 * 8;
    float xa[32];
    #pragma unroll
    for (int j = 0; j < 4; ++j) {
        float4 p0 = *(const float4*)(priors + gbaseA + j * 128);
        float4 p1 = *(const float4*)(priors + gbaseA + j * 128 + 4);
        xa[j*8+0] = p0.x; xa[j*8+1] = p0.y; xa[j*8+2] = p0.z; xa[j*8+3] = p0.w;
        xa[j*8+4] = p1.x; xa[j*8+5] = p1.y; xa[j*8+6] = p1.z; xa[j*8+7] = p1.w;
    }
    __syncthreads();

    // ---- Phase 4, pass A: rows w*8 + quad ----
    {
        const int r = w * 8 + quad;
        #pragma unroll
        for (int j = 0; j < 4; ++j) {
            // bank-balanced: 8 lanes per 16B slot, all 32 banks uniformly hit
            half8 h = *(const half8*)&tile[r][i16 * 8 + j * 128];
            xa[j*8+0] *= (float)h[0]; xa[j*8+1] *= (float)h[1];
            xa[j*8+2] *= (float)h[2]; xa[j*8+3] *= (float)h[3];
            xa[j*8+4] *= (float)h[4]; xa[j*8+5] *= (float)h[5];
            xa[j*8+6] *= (float)h[6]; xa[j*8+7] *= (float)h[7];
        }
        sparsemax_row32(xa, out + gbaseA);
    }

    // ---- Phase 4, pass B: rows w*8 + 4 + quad ----
    // Loads batch-issued here (after pass-A stores): one exposed HBM
    // latency (~1k cyc) per block, then pipelined.
    const size_t gbaseB = gbaseA + (size_t)4 * OUTDIM;
    float xb[32];
    #pragma unroll
    for (int j = 0; j < 4; ++j) {
        float4 p0 = *(const float4*)(priors + gbaseB + j * 128);
        float4 p1 = *(const float4*)(priors + gbaseB + j * 128 + 4);
        xb[j*8+0] = p0.x; xb[j*8+1] = p0.y; xb[j*8+2] = p0.z; xb[j*8+3] = p0.w;
        xb[j*8+4] = p1.x; xb[j*8+5] = p1.y; xb[j*8+6] = p1.z; xb[j*8+7] = p1.w;
    }
    {
        const int r = w * 8 + 4 + quad;
        #pragma unroll
        for (int j = 0; j < 4; ++j) {
            half8 h = *(const half8*)&tile[r][i16 * 8 + j * 128];
            xb[j*8+0] *= (float)h[0]; xb[j*8+1] *= (float)h[1];
            xb[j*8+2] *= (float)h[2]; xb[j*8+3] *= (float)h[3];
            xb[j*8+4] *= (float)h[4]; xb[j*8+5] *= (float)h[5];
            xb[j*8+6] *= (float)h[6]; xb[j*8+7] *= (float)h[7];
        }
        sparsemax_row32(xb, out + gbaseB);
    }
}

// ---------------------------------------------------------------------------
extern "C" void kernel_launch(void* const* d_in, const int* in_sizes, int n_in,
                              void* d_out, int out_size, void* d_ws, size_t ws_size,
                              hipStream_t stream) {
    const float* priors = (const float*)d_in[0];
    const float* feat   = (const float*)d_in[1];
    const float* W      = (const float*)d_in[2];
    const float* gamma  = (const float*)d_in[3];
    const float* beta   = (const float*)d_in[4];
    float* out = (float*)d_out;
    _Float16* Wh = (_Float16*)d_ws;   // 512*128*2 = 128 KB, only ws use

    hipLaunchKernelGGL(w_to_half_kernel, dim3(64), dim3(256), 0, stream, W, Wh);
    hipLaunchKernelGGL(fused_all, dim3(NCHUNK), dim3(1024), 0, stream,
                       priors, feat, Wh, gamma, beta, out);
}